// Round 1
// baseline (1044.531 us; speedup 1.0000x reference)
//
#include <hip/hip_runtime.h>
#include <math.h>

#define HD   64
#define EIN  8
#define DIN  136          // 2*HD + EIN
#define NORM_INV 0.01f    // 1/NORM_FACTOR

__global__ void copy_coord_kernel(const float* __restrict__ coord,
                                  float* __restrict__ out, int n) {
    int i = blockIdx.x * blockDim.x + threadIdx.x;
    if (i < n) out[i] = coord[i];
}

__device__ __forceinline__ float silu_f(float x) {
    // x * sigmoid(x); approx rcp/exp are fine: result is scaled by ~3e-6 downstream
    return x * __builtin_amdgcn_rcpf(1.0f + __expf(-x));
}

__global__ __launch_bounds__(256) void egnn_edge_kernel(
    const float* __restrict__ h,
    const float* __restrict__ coord,
    const int*   __restrict__ eidx,      // [2, E] flat
    const float* __restrict__ edge_attr, // [E, 8]
    const float* __restrict__ W1,        // [136, 64] row-major
    const float* __restrict__ b1,        // [64]
    const float* __restrict__ W2,        // [64, 64]
    const float* __restrict__ b2,        // [64]
    const float* __restrict__ W3,        // [64]
    float* __restrict__ out,             // [N, 3], pre-initialized to coord
    int E_)
{
    __shared__ float sW1[DIN * HD];   // 34.8 KB, row-major [k][j]
    __shared__ float sW2t[HD * HD];   // 16.4 KB, TRANSPOSED [j][k]
    __shared__ float sb1[HD], sb2[HD], sW3[HD];

    for (int i = threadIdx.x; i < DIN * HD; i += 256) sW1[i] = W1[i];
    for (int i = threadIdx.x; i < HD * HD; i += 256) {
        int k = i >> 6, j = i & 63;
        sW2t[j * HD + k] = W2[i];
    }
    if (threadIdx.x < HD) {
        sb1[threadIdx.x] = b1[threadIdx.x];
        sb2[threadIdx.x] = b2[threadIdx.x];
        sW3[threadIdx.x] = W3[threadIdx.x];
    }
    __syncthreads();

    int e = blockIdx.x * 256 + threadIdx.x;
    if (e >= E_) return;

    int row = eidx[e];
    int col = eidx[E_ + e];

    // ---- coord2diff (norm_constant = 1) ----
    float cdx = coord[row * 3 + 0] - coord[col * 3 + 0];
    float cdy = coord[row * 3 + 1] - coord[col * 3 + 1];
    float cdz = coord[row * 3 + 2] - coord[col * 3 + 2];
    float radial = cdx * cdx + cdy * cdy + cdz * cdz;
    float nrm = sqrtf(radial + 1e-8f);
    float inv = __builtin_amdgcn_rcpf(nrm + 1.0f);
    cdx *= inv; cdy *= inv; cdz *= inv;

    // ---- layer 1: x1 = silu(inp @ W1 + b1) ----
    float acc[HD];
#pragma unroll
    for (int j = 0; j < HD; ++j) acc[j] = sb1[j];

    const float4* hr = reinterpret_cast<const float4*>(h + (size_t)row * HD);
    const float4* hc = reinterpret_cast<const float4*>(h + (size_t)col * HD);
    const float4* ea = reinterpret_cast<const float4*>(edge_attr + (size_t)e * EIN);

    // k runtime (LDS addr only), j compile-time (register array) -> no scratch
    auto fma_k = [&](int k, float a) {
        const float4* w = reinterpret_cast<const float4*>(sW1 + k * HD);
#pragma unroll
        for (int jj = 0; jj < HD / 4; ++jj) {
            float4 wv = w[jj];           // wave-uniform addr -> LDS broadcast
            acc[4 * jj + 0] += a * wv.x;
            acc[4 * jj + 1] += a * wv.y;
            acc[4 * jj + 2] += a * wv.z;
            acc[4 * jj + 3] += a * wv.w;
        }
    };

    for (int kk = 0; kk < HD / 4; ++kk) {          // h[row] part, k = 0..63
        float4 av = hr[kk];
        fma_k(4 * kk + 0, av.x);
        fma_k(4 * kk + 1, av.y);
        fma_k(4 * kk + 2, av.z);
        fma_k(4 * kk + 3, av.w);
    }
    for (int kk = 0; kk < HD / 4; ++kk) {          // h[col] part, k = 64..127
        float4 av = hc[kk];
        fma_k(HD + 4 * kk + 0, av.x);
        fma_k(HD + 4 * kk + 1, av.y);
        fma_k(HD + 4 * kk + 2, av.z);
        fma_k(HD + 4 * kk + 3, av.w);
    }
    {                                               // edge_attr part, k = 128..135
        float4 a0 = ea[0];
        fma_k(128, a0.x); fma_k(129, a0.y); fma_k(130, a0.z); fma_k(131, a0.w);
        float4 a1 = ea[1];
        fma_k(132, a1.x); fma_k(133, a1.y); fma_k(134, a1.z); fma_k(135, a1.w);
    }

#pragma unroll
    for (int j = 0; j < HD; ++j) acc[j] = silu_f(acc[j]);   // s1 in place

    // ---- layers 2+3 fused: scal = silu(s1 @ W2 + b2) @ W3 ----
    // j rolled (LDS addr runtime ok), k unrolled (register index compile-time)
    float scal = 0.0f;
    for (int j = 0; j < HD; ++j) {
        float t = sb2[j];
        const float4* w = reinterpret_cast<const float4*>(sW2t + j * HD);
#pragma unroll
        for (int kk = 0; kk < HD / 4; ++kk) {
            float4 wv = w[kk];           // wave-uniform addr -> LDS broadcast
            t += acc[4 * kk + 0] * wv.x + acc[4 * kk + 1] * wv.y
               + acc[4 * kk + 2] * wv.z + acc[4 * kk + 3] * wv.w;
        }
        scal += silu_f(t) * sW3[j];
    }

    // ---- trans = coord_diff * scal ; scatter-add agg/100 into out ----
    float s = scal * NORM_INV;
    atomicAdd(&out[row * 3 + 0], cdx * s);
    atomicAdd(&out[row * 3 + 1], cdy * s);
    atomicAdd(&out[row * 3 + 2], cdz * s);
}

extern "C" void kernel_launch(void* const* d_in, const int* in_sizes, int n_in,
                              void* d_out, int out_size, void* d_ws, size_t ws_size,
                              hipStream_t stream) {
    const float* h         = (const float*)d_in[0];
    const float* coord     = (const float*)d_in[1];
    const int*   eidx      = (const int*)  d_in[2];
    const float* edge_attr = (const float*)d_in[3];
    const float* W1        = (const float*)d_in[4];
    const float* b1        = (const float*)d_in[5];
    const float* W2        = (const float*)d_in[6];
    const float* b2        = (const float*)d_in[7];
    const float* W3        = (const float*)d_in[8];
    float* out = (float*)d_out;

    int E_ = in_sizes[2] / 2;   // edge_index is [2, E]
    int n3 = out_size;          // N*3

    hipLaunchKernelGGL(copy_coord_kernel, dim3((n3 + 255) / 256), dim3(256), 0, stream,
                       coord, out, n3);
    hipLaunchKernelGGL(egnn_edge_kernel, dim3((E_ + 255) / 256), dim3(256), 0, stream,
                       h, coord, eidx, edge_attr, W1, b1, W2, b2, W3, out, E_);
}

// Round 2
// 897.291 us; speedup vs baseline: 1.1641x; 1.1641x over previous
//
#include <hip/hip_runtime.h>
#include <math.h>

#define HD   64
#define EIN  8
#define NORM_INV 0.01f    // 1/NORM_FACTOR

// Copies coord -> out and writes W2^T into workspace (both needed fresh every call).
__global__ void prep_kernel(const float* __restrict__ coord,
                            float* __restrict__ out, int n3,
                            const float* __restrict__ W2,
                            float* __restrict__ W2t) {
    int i = blockIdx.x * blockDim.x + threadIdx.x;
    if (i < n3) out[i] = coord[i];
    if (i < HD * HD) W2t[(i & 63) * HD + (i >> 6)] = W2[i];
}

__device__ __forceinline__ float silu_f(float x) {
    return x * __builtin_amdgcn_rcpf(1.0f + __expf(-x));
}

__global__ __launch_bounds__(256, 4) void egnn_edge_kernel(
    const float* __restrict__ h,
    const float* __restrict__ coord,
    const int*   __restrict__ eidx,      // [2, E] flat
    const float* __restrict__ edge_attr, // [E, 8]
    const float* __restrict__ W1,        // [136, 64] row-major (uniform -> s_load)
    const float* __restrict__ b1,        // [64]
    const float* __restrict__ W2t,       // [64, 64] transposed, in ws
    const float* __restrict__ b2,        // [64]
    const float* __restrict__ W3,        // [64]
    float* __restrict__ out,             // [N, 3], pre-initialized to coord
    int E_)
{
    int e = blockIdx.x * 256 + threadIdx.x;
    if (e >= E_) return;

    int row = eidx[e];
    int col = eidx[E_ + e];

    // Kick off per-edge gathers early (VMEM latency overlaps scalar weight loads)
    const float4* hr = reinterpret_cast<const float4*>(h + (size_t)row * HD);
    const float4* hc = reinterpret_cast<const float4*>(h + (size_t)col * HD);
    const float4* ea = reinterpret_cast<const float4*>(edge_attr + (size_t)e * EIN);
    float4 ea0 = ea[0];
    float4 ea1 = ea[1];
    float crx = coord[row * 3 + 0], cry = coord[row * 3 + 1], crz = coord[row * 3 + 2];
    float ccx = coord[col * 3 + 0], ccy = coord[col * 3 + 1], ccz = coord[col * 3 + 2];

    // ---- coord2diff (norm_constant = 1) ----
    float cdx = crx - ccx, cdy = cry - ccy, cdz = crz - ccz;
    float radial = cdx * cdx + cdy * cdy + cdz * cdz;
    float inv = __builtin_amdgcn_rcpf(sqrtf(radial + 1e-8f) + 1.0f);
    cdx *= inv; cdy *= inv; cdz *= inv;

    // ---- layer 1: acc = inp @ W1 + b1 ----
    // Weight rows are wave-uniform global loads -> s_load into SGPRs (scalar pipe),
    // v_fma takes the SGPR operand directly. No LDS anywhere in this kernel.
    float acc[HD];
#pragma unroll
    for (int j = 0; j < HD; ++j) acc[j] = b1[j];

    auto fma_row = [&](const float* __restrict__ w, float a) {
#pragma unroll
        for (int j = 0; j < HD; ++j) acc[j] = fmaf(a, w[j], acc[j]);
    };

    for (int kk = 0; kk < HD / 4; ++kk) {          // k = 0..63   (h[row])
        float4 av = hr[kk];
        fma_row(W1 + (4 * kk + 0) * HD, av.x);
        fma_row(W1 + (4 * kk + 1) * HD, av.y);
        fma_row(W1 + (4 * kk + 2) * HD, av.z);
        fma_row(W1 + (4 * kk + 3) * HD, av.w);
    }
    for (int kk = 0; kk < HD / 4; ++kk) {          // k = 64..127 (h[col])
        float4 av = hc[kk];
        fma_row(W1 + (HD + 4 * kk + 0) * HD, av.x);
        fma_row(W1 + (HD + 4 * kk + 1) * HD, av.y);
        fma_row(W1 + (HD + 4 * kk + 2) * HD, av.z);
        fma_row(W1 + (HD + 4 * kk + 3) * HD, av.w);
    }
    {                                               // k = 128..135 (edge_attr)
        fma_row(W1 + 128 * HD, ea0.x); fma_row(W1 + 129 * HD, ea0.y);
        fma_row(W1 + 130 * HD, ea0.z); fma_row(W1 + 131 * HD, ea0.w);
        fma_row(W1 + 132 * HD, ea1.x); fma_row(W1 + 133 * HD, ea1.y);
        fma_row(W1 + 134 * HD, ea1.z); fma_row(W1 + 135 * HD, ea1.w);
    }

#pragma unroll
    for (int j = 0; j < HD; ++j) acc[j] = silu_f(acc[j]);   // s1 in place

    // ---- layers 2+3 fused: scal = silu(s1 @ W2 + b2) @ W3 ----
    // j rolled (uniform scalar loads per row of W2t), k unrolled (compile-time
    // register indices into acc). 4 partial sums break the FMA dependency chain.
    float scal = 0.0f;
    for (int j = 0; j < HD; ++j) {
        const float* w = W2t + j * HD;             // uniform -> s_load
        float t0 = b2[j], t1 = 0.f, t2 = 0.f, t3 = 0.f;
#pragma unroll
        for (int k = 0; k < HD; k += 4) {
            t0 = fmaf(acc[k + 0], w[k + 0], t0);
            t1 = fmaf(acc[k + 1], w[k + 1], t1);
            t2 = fmaf(acc[k + 2], w[k + 2], t2);
            t3 = fmaf(acc[k + 3], w[k + 3], t3);
        }
        float t = (t0 + t1) + (t2 + t3);
        scal = fmaf(silu_f(t), W3[j], scal);
    }

    // ---- trans = coord_diff * scal ; scatter-add agg/100 into out ----
    float s = scal * NORM_INV;
    atomicAdd(&out[row * 3 + 0], cdx * s);
    atomicAdd(&out[row * 3 + 1], cdy * s);
    atomicAdd(&out[row * 3 + 2], cdz * s);
}

extern "C" void kernel_launch(void* const* d_in, const int* in_sizes, int n_in,
                              void* d_out, int out_size, void* d_ws, size_t ws_size,
                              hipStream_t stream) {
    const float* h         = (const float*)d_in[0];
    const float* coord     = (const float*)d_in[1];
    const int*   eidx      = (const int*)  d_in[2];
    const float* edge_attr = (const float*)d_in[3];
    const float* W1        = (const float*)d_in[4];
    const float* b1        = (const float*)d_in[5];
    const float* W2        = (const float*)d_in[6];
    const float* b2        = (const float*)d_in[7];
    const float* W3        = (const float*)d_in[8];
    float* out = (float*)d_out;
    float* W2t = (float*)d_ws;   // 64*64 floats = 16 KB scratch

    int E_ = in_sizes[2] / 2;    // edge_index is [2, E]
    int n3 = out_size;           // N*3

    hipLaunchKernelGGL(prep_kernel, dim3((n3 + 255) / 256), dim3(256), 0, stream,
                       coord, out, n3, W2, W2t);
    hipLaunchKernelGGL(egnn_edge_kernel, dim3((E_ + 255) / 256), dim3(256), 0, stream,
                       h, coord, eidx, edge_attr, W1, b1, W2t, b2, W3, out, E_);
}